// Round 2
// baseline (652.567 us; speedup 1.0000x reference)
//
#include <hip/hip_runtime.h>
#include <hip/hip_cooperative_groups.h>
#include <cstdint>
#include <cstddef>

namespace cg = cooperative_groups;

// Problem constants
#define BB   8
#define TT   4096
#define DD   512
#define UU   512
#define NN   1536   // 3*UU
#define KK   1024   // 2*DD
#define MM   32768  // BB*TT
#define NCH  128    // number of scan chunks
#define CHL  32     // chunk length (NCH*CHL == TT)

using bf16x8 = __attribute__((ext_vector_type(8))) __bf16;
using f32x4  = __attribute__((ext_vector_type(4))) float;

__device__ __forceinline__ unsigned short f2bf(float f) {
    unsigned u = __float_as_uint(f);
    u += 0x7fffu + ((u >> 16) & 1u);   // RTNE
    return (unsigned short)(u >> 16);
}
__device__ __forceinline__ float bf2f(unsigned short s) {
    return __uint_as_float(((unsigned)s) << 16);
}
__device__ __forceinline__ float sigf(float x) { return 1.0f / (1.0f + __expf(-x)); }
__device__ __forceinline__ float tanh_(float x) { return 1.0f - 2.0f / (1.0f + __expf(2.0f * x)); }

__device__ __forceinline__ void async16(const void* g, void* l) {
    __builtin_amdgcn_global_load_lds(
        (__attribute__((address_space(1))) void*)g,
        (__attribute__((address_space(3))) void*)l, 16, 0, 0);
}

// ---- 1) prep: pad+convert x -> xpad (bf16), and transpose kernel -> kT ----
// grid: dim3(2049 + 24, 8).  x-blocks < 2049 do pad for batch y;
// x-blocks >= 2049 each transpose 8 of the 1536 32x32 tiles.
__global__ void k_prep(const float* __restrict__ x, unsigned short* __restrict__ xpad,
                       const float* __restrict__ kern, unsigned short* __restrict__ kT) {
    int bx = blockIdx.x;
    int by = blockIdx.y;
    int tid = threadIdx.x;
    if (bx < 2049) {
        int q = bx * 256 + tid;              // quad index within batch
        if (q >= 4097 * 128) return;
        int tp = q >> 7;                     // 0..4096
        int d  = (q & 127) << 2;             // 0..508
        size_t oi = ((size_t)by * 4097 + tp) * 512 + d;
        ushort4 o;
        if (tp == 0) {
            o.x = o.y = o.z = o.w = 0;
        } else {
            float4 v = *(const float4*)(x + ((size_t)by * 4096 + (tp - 1)) * 512 + d);
            o.x = f2bf(v.x); o.y = f2bf(v.y); o.z = f2bf(v.z); o.w = f2bf(v.w);
        }
        *(ushort4*)(xpad + oi) = o;
    } else {
        __shared__ float tile[32][33];
        int idx = (bx - 2049) * 8 + by;      // 0..191
        int c  = tid & 31;
        int r0 = tid >> 5;                   // 0..7
        for (int t8 = 0; t8 < 8; ++t8) {
            int tnum = idx * 8 + t8;         // 0..1535
            int k0 = (tnum & 31) * 32;       // 32 K-tiles
            int n0 = (tnum >> 5) * 32;       // 48 N-tiles
#pragma unroll
            for (int rr = r0; rr < 32; rr += 8)
                tile[rr][c] = kern[(size_t)(k0 + rr) * NN + n0 + c];
            __syncthreads();
#pragma unroll
            for (int rr = r0; rr < 32; rr += 8)
                kT[(size_t)(n0 + rr) * KK + k0 + c] = f2bf(tile[c][rr]);
            __syncthreads();
        }
    }
}

// ---- 2) GEMM: gates[m][n] = A[m][:] * kT[n][:]^T + bias[n], stored bf16 ----
// A row m = xpad_flat[(m + (m>>12))*512 ... +1024)  (contiguous window)
// 1D grid of 3072 blocks, XCD-aware swizzle: xcd = bid&7 owns 32 consecutive
// m-tiles, iterates its 12 n-tiles fastest -> A fetched once per XCD,
// kT (3 MB) stays resident in each XCD's 4 MB L2.
__global__ __launch_bounds__(256) void k_gemm(
    const unsigned short* __restrict__ xpad,
    const unsigned short* __restrict__ kT,
    const float* __restrict__ bias,
    unsigned short* __restrict__ gates)
{
    __shared__ unsigned short As[128 * 64];
    __shared__ unsigned short Bs[128 * 64];
    const int tid  = threadIdx.x;
    const int bi   = blockIdx.x;
    const int xcd  = bi & 7;
    const int loc  = bi >> 3;            // 0..383
    const int mt   = xcd * 32 + loc / 12;
    const int nt   = loc % 12;
    const int m0   = mt * 128;
    const int n0   = nt * 128;
    const int boff = m0 >> 12;           // batch index of the whole tile
    const size_t abase = (size_t)(m0 + boff) * 512;

    f32x4 acc[4][4] = {};

    const int wid  = tid >> 6;
    const int lane = tid & 63;
    const int wm   = (wid & 1) * 64;
    const int wn   = (wid >> 1) * 64;
    const int lrow = lane & 15;
    const int quad = lane >> 4;

    for (int kk = 0; kk < KK; kk += 64) {
        // stage A-tile [128 rows][64 k] and B-tile [128 n][64 k], 16B/lane,
        // XOR-swizzled 16B segments: LDS slot (row*8+sp) holds segment sp^(row&7)
#pragma unroll
        for (int q = 0; q < 4; ++q) {
            int L   = q * 256 + tid;
            int row = L >> 3;
            int sp  = L & 7;
            int sl  = sp ^ (row & 7);
            async16(xpad + abase + (size_t)row * 512 + kk + sl * 8, As + (size_t)L * 8);
            async16(kT + (size_t)(n0 + row) * KK + kk + sl * 8, Bs + (size_t)L * 8);
        }
        __syncthreads();
#pragma unroll
        for (int ks = 0; ks < 2; ++ks) {
            bf16x8 af[4], bfr[4];
#pragma unroll
            for (int i = 0; i < 4; ++i) {
                int row = wm + i * 16 + lrow;
                int sp  = (ks * 4 + quad) ^ (row & 7);
                af[i] = *(const bf16x8*)(As + row * 64 + sp * 8);
            }
#pragma unroll
            for (int j = 0; j < 4; ++j) {
                int row = wn + j * 16 + lrow;
                int sp  = (ks * 4 + quad) ^ (row & 7);
                bfr[j] = *(const bf16x8*)(Bs + row * 64 + sp * 8);
            }
#pragma unroll
            for (int i = 0; i < 4; ++i)
#pragma unroll
                for (int j = 0; j < 4; ++j)
                    acc[i][j] = __builtin_amdgcn_mfma_f32_16x16x32_bf16(af[i], bfr[j], acc[i][j], 0, 0, 0);
        }
        __syncthreads();
    }

    // epilogue: C/D layout col=lane&15, row=quad*4+reg  [m89-verified]
#pragma unroll
    for (int j = 0; j < 4; ++j) {
        int col  = n0 + wn + j * 16 + lrow;
        float bv = bias[col];
#pragma unroll
        for (int i = 0; i < 4; ++i) {
            int rbase = m0 + wm + i * 16 + quad * 4;
#pragma unroll
            for (int r = 0; r < 4; ++r) {
                gates[(size_t)(rbase + r) * NN + col] = f2bf(acc[i][j][r] + bv);
            }
        }
    }
}

// ---- 3) fused 3-phase scan (cooperative, 1024 blocks x 128 threads) ----
// Phase A: per-chunk local scan + running f-product  -> Fp, Ce
// Phase B: 4096 scalar threads scan across the 128 chunks -> Cin
// Phase C: replay chunk with true carry-in, emit out = o * c
__global__ __launch_bounds__(128) void k_scan(
    const unsigned short* __restrict__ gates,
    float* __restrict__ Fp, float* __restrict__ Ce, float* __restrict__ Cin,
    float* __restrict__ out)
{
    cg::grid_group grid = cg::this_grid();
    const int bid   = blockIdx.x;        // 0..1023
    const int chunk = bid & 127;
    const int b     = bid >> 7;
    const int u     = threadIdx.x << 2;  // 128 threads * 4 units

    // ---------- Phase A ----------
    {
        float c0 = 0, c1 = 0, c2 = 0, c3 = 0;
        float F0 = 1, F1 = 1, F2 = 1, F3 = 1;
        size_t g = ((size_t)b * TT + (size_t)chunk * CHL) * NN + u;
#pragma unroll 4
        for (int i = 0; i < CHL; ++i) {
            ushort4 gz = *(const ushort4*)(gates + g);
            ushort4 gf = *(const ushort4*)(gates + g + UU);
            g += NN;
            float f0 = sigf(bf2f(gf.x)), z0 = tanh_(bf2f(gz.x));
            float f1 = sigf(bf2f(gf.y)), z1 = tanh_(bf2f(gz.y));
            float f2 = sigf(bf2f(gf.z)), z2 = tanh_(bf2f(gz.z));
            float f3 = sigf(bf2f(gf.w)), z3 = tanh_(bf2f(gz.w));
            c0 = f0 * c0 + (1.0f - f0) * z0; F0 *= f0;
            c1 = f1 * c1 + (1.0f - f1) * z1; F1 *= f1;
            c2 = f2 * c2 + (1.0f - f2) * z2; F2 *= f2;
            c3 = f3 * c3 + (1.0f - f3) * z3; F3 *= f3;
        }
        size_t ci = ((size_t)b * NCH + chunk) * UU + u;
        *(float4*)(Fp + ci) = make_float4(F0, F1, F2, F3);
        *(float4*)(Ce + ci) = make_float4(c0, c1, c2, c3);
    }
    __threadfence();
    grid.sync();

    // ---------- Phase B ----------
    {
        int gid = bid * 128 + threadIdx.x;
        if (gid < BB * UU) {
            int bb = gid >> 9;           // batch
            int uu = gid & 511;          // unit
            size_t base = (size_t)bb * NCH * UU + uu;
            float c = 0.0f;
#pragma unroll
            for (int k0 = 0; k0 < NCH; k0 += 8) {
                float F[8], E[8];
#pragma unroll
                for (int j = 0; j < 8; ++j) {
                    F[j] = Fp[base + (size_t)(k0 + j) * UU];
                    E[j] = Ce[base + (size_t)(k0 + j) * UU];
                }
#pragma unroll
                for (int j = 0; j < 8; ++j) {
                    Cin[base + (size_t)(k0 + j) * UU] = c;
                    c = F[j] * c + E[j];
                }
            }
        }
    }
    __threadfence();
    grid.sync();

    // ---------- Phase C ----------
    {
        size_t ci = ((size_t)b * NCH + chunk) * UU + u;
        float4 cv = *(const float4*)(Cin + ci);
        float c0 = cv.x, c1 = cv.y, c2 = cv.z, c3 = cv.w;
        size_t g = ((size_t)b * TT + (size_t)chunk * CHL) * NN + u;
        size_t o = ((size_t)b * TT + (size_t)chunk * CHL) * UU + u;
#pragma unroll 4
        for (int i = 0; i < CHL; ++i) {
            ushort4 gz = *(const ushort4*)(gates + g);
            ushort4 gf = *(const ushort4*)(gates + g + UU);
            ushort4 go = *(const ushort4*)(gates + g + 2 * UU);
            g += NN;
            float f0 = sigf(bf2f(gf.x)), z0 = tanh_(bf2f(gz.x)), o0 = sigf(bf2f(go.x));
            float f1 = sigf(bf2f(gf.y)), z1 = tanh_(bf2f(gz.y)), o1 = sigf(bf2f(go.y));
            float f2 = sigf(bf2f(gf.z)), z2 = tanh_(bf2f(gz.z)), o2 = sigf(bf2f(go.z));
            float f3 = sigf(bf2f(gf.w)), z3 = tanh_(bf2f(gz.w)), o3 = sigf(bf2f(go.w));
            c0 = f0 * c0 + (1.0f - f0) * z0;
            c1 = f1 * c1 + (1.0f - f1) * z1;
            c2 = f2 * c2 + (1.0f - f2) * z2;
            c3 = f3 * c3 + (1.0f - f3) * z3;
            *(float4*)(out + o) = make_float4(o0 * c0, o1 * c1, o2 * c2, o3 * c3);
            o += UU;
        }
    }
}

extern "C" void kernel_launch(void* const* d_in, const int* in_sizes, int n_in,
                              void* d_out, int out_size, void* d_ws, size_t ws_size,
                              hipStream_t stream) {
    const float* x    = (const float*)d_in[0];
    const float* kern = (const float*)d_in[1];
    const float* bias = (const float*)d_in[2];
    float* out = (float*)d_out;
    char* ws = (char*)d_ws;

    // workspace layout (bytes)
    unsigned short* xpad  = (unsigned short*)(ws + 0);           // 8*4097*512*2   = 33,562,624
    unsigned short* kT    = (unsigned short*)(ws + 33562624);    // 1536*1024*2    =  3,145,728
    unsigned short* gates = (unsigned short*)(ws + 36708352);    // 32768*1536*2   = 100,663,296
    float* Fp  = (float*)(ws + 137371648);                       // 8*128*512*4    =  2,097,152
    float* Ce  = (float*)(ws + 139468800);                       //                =  2,097,152
    float* Cin = (float*)(ws + 141565952);                       //                =  2,097,152
    // total: 143,663,104 bytes

    hipLaunchKernelGGL(k_prep, dim3(2049 + 24, 8), dim3(256), 0, stream, x, xpad, kern, kT);
    hipLaunchKernelGGL(k_gemm, dim3(3072), dim3(256), 0, stream, xpad, kT, bias, gates);

    void* args[] = { (void*)&gates, (void*)&Fp, (void*)&Ce, (void*)&Cin, (void*)&out };
    hipLaunchCooperativeKernel((void*)k_scan, dim3(1024), dim3(128), args, 0, stream);
}

// Round 4
// 327.138 us; speedup vs baseline: 1.9948x; 1.9948x over previous
//
#include <hip/hip_runtime.h>
#include <cstdint>
#include <cstddef>

// Problem constants
#define BB   8
#define TT   4096
#define DD   512
#define UU   512
#define NN   1536   // 3*UU
#define KK   1024   // 2*DD
#define MM   32768  // BB*TT
#define NCH  256    // number of scan chunks
#define CHL  16     // chunk length (NCH*CHL == TT)

using bf16x8 = __attribute__((ext_vector_type(8))) __bf16;
using f32x4  = __attribute__((ext_vector_type(4))) float;

__device__ __forceinline__ unsigned short f2bf(float f) {
    unsigned u = __float_as_uint(f);
    u += 0x7fffu + ((u >> 16) & 1u);   // RTNE
    return (unsigned short)(u >> 16);
}
__device__ __forceinline__ float bf2f(unsigned short s) {
    return __uint_as_float(((unsigned)s) << 16);
}
__device__ __forceinline__ float sigf(float x) { return 1.0f / (1.0f + __expf(-x)); }
__device__ __forceinline__ float tanh_(float x) { return 1.0f - 2.0f / (1.0f + __expf(2.0f * x)); }

__device__ __forceinline__ void async16(const void* g, void* l) {
    __builtin_amdgcn_global_load_lds(
        (__attribute__((address_space(1))) void*)g,
        (__attribute__((address_space(3))) void*)l, 16, 0, 0);
}

// ---- 1) prep: pad+convert x -> xpad (bf16), and transpose kernel -> kT ----
__global__ void k_prep(const float* __restrict__ x, unsigned short* __restrict__ xpad,
                       const float* __restrict__ kern, unsigned short* __restrict__ kT) {
    int bx = blockIdx.x;
    int by = blockIdx.y;
    int tid = threadIdx.x;
    if (bx < 2049) {
        int q = bx * 256 + tid;              // quad index within batch
        if (q >= 4097 * 128) return;
        int tp = q >> 7;                     // 0..4096
        int d  = (q & 127) << 2;             // 0..508
        size_t oi = ((size_t)by * 4097 + tp) * 512 + d;
        ushort4 o;
        if (tp == 0) {
            o.x = o.y = o.z = o.w = 0;
        } else {
            float4 v = *(const float4*)(x + ((size_t)by * 4096 + (tp - 1)) * 512 + d);
            o.x = f2bf(v.x); o.y = f2bf(v.y); o.z = f2bf(v.z); o.w = f2bf(v.w);
        }
        *(ushort4*)(xpad + oi) = o;
    } else {
        __shared__ float tile[32][33];
        int idx = (bx - 2049) * 8 + by;      // 0..191
        int c  = tid & 31;
        int r0 = tid >> 5;                   // 0..7
        for (int t8 = 0; t8 < 8; ++t8) {
            int tnum = idx * 8 + t8;         // 0..1535
            int k0 = (tnum & 31) * 32;       // 32 K-tiles
            int n0 = (tnum >> 5) * 32;       // 48 N-tiles
#pragma unroll
            for (int rr = r0; rr < 32; rr += 8)
                tile[rr][c] = kern[(size_t)(k0 + rr) * NN + n0 + c];
            __syncthreads();
#pragma unroll
            for (int rr = r0; rr < 32; rr += 8)
                kT[(size_t)(n0 + rr) * KK + k0 + c] = f2bf(tile[c][rr]);
            __syncthreads();
        }
    }
}

// ---- 2) GEMM: gates[m][n] = A[m][:] * kT[n][:]^T + bias[n], stored bf16 ----
__global__ __launch_bounds__(256) void k_gemm(
    const unsigned short* __restrict__ xpad,
    const unsigned short* __restrict__ kT,
    const float* __restrict__ bias,
    unsigned short* __restrict__ gates)
{
    __shared__ unsigned short As[128 * 64];
    __shared__ unsigned short Bs[128 * 64];
    const int tid  = threadIdx.x;
    const int bi   = blockIdx.x;
    const int xcd  = bi & 7;
    const int loc  = bi >> 3;            // 0..383
    const int mt   = xcd * 32 + loc / 12;
    const int nt   = loc % 12;
    const int m0   = mt * 128;
    const int n0   = nt * 128;
    const int boff = m0 >> 12;           // batch index of the whole tile
    const size_t abase = (size_t)(m0 + boff) * 512;

    f32x4 acc[4][4] = {};

    const int wid  = tid >> 6;
    const int lane = tid & 63;
    const int wm   = (wid & 1) * 64;
    const int wn   = (wid >> 1) * 64;
    const int lrow = lane & 15;
    const int quad = lane >> 4;

    for (int kk = 0; kk < KK; kk += 64) {
#pragma unroll
        for (int q = 0; q < 4; ++q) {
            int L   = q * 256 + tid;
            int row = L >> 3;
            int sp  = L & 7;
            int sl  = sp ^ (row & 7);
            async16(xpad + abase + (size_t)row * 512 + kk + sl * 8, As + (size_t)L * 8);
            async16(kT + (size_t)(n0 + row) * KK + kk + sl * 8, Bs + (size_t)L * 8);
        }
        __syncthreads();
#pragma unroll
        for (int ks = 0; ks < 2; ++ks) {
            bf16x8 af[4], bfr[4];
#pragma unroll
            for (int i = 0; i < 4; ++i) {
                int row = wm + i * 16 + lrow;
                int sp  = (ks * 4 + quad) ^ (row & 7);
                af[i] = *(const bf16x8*)(As + row * 64 + sp * 8);
            }
#pragma unroll
            for (int j = 0; j < 4; ++j) {
                int row = wn + j * 16 + lrow;
                int sp  = (ks * 4 + quad) ^ (row & 7);
                bfr[j] = *(const bf16x8*)(Bs + row * 64 + sp * 8);
            }
#pragma unroll
            for (int i = 0; i < 4; ++i)
#pragma unroll
                for (int j = 0; j < 4; ++j)
                    acc[i][j] = __builtin_amdgcn_mfma_f32_16x16x32_bf16(af[i], bfr[j], acc[i][j], 0, 0, 0);
        }
        __syncthreads();
    }

#pragma unroll
    for (int j = 0; j < 4; ++j) {
        int col  = n0 + wn + j * 16 + lrow;
        float bv = bias[col];
#pragma unroll
        for (int i = 0; i < 4; ++i) {
            int rbase = m0 + wm + i * 16 + quad * 4;
#pragma unroll
            for (int r = 0; r < 4; ++r) {
                gates[(size_t)(rbase + r) * NN + col] = f2bf(acc[i][j][r] + bv);
            }
        }
    }
}

// ---- 3) pass A: per-chunk local scan + running f-product (batched loads) ----
__global__ __launch_bounds__(128) void k_scanA(const unsigned short* __restrict__ gates,
                        float* __restrict__ Fp, float* __restrict__ Ce) {
    const int chunk = blockIdx.x;        // 0..255
    const int b     = blockIdx.y;        // 0..7
    const int u     = threadIdx.x << 2;  // 128 threads * 4
    const size_t g0 = ((size_t)b * TT + (size_t)chunk * CHL) * NN + u;

    float c0 = 0, c1 = 0, c2 = 0, c3 = 0;
    float F0 = 1, F1 = 1, F2 = 1, F3 = 1;

    ushort4 bz[8], bf_[8];
#pragma unroll
    for (int j = 0; j < 8; ++j) {
        bz[j]  = *(const ushort4*)(gates + g0 + (size_t)j * NN);
        bf_[j] = *(const ushort4*)(gates + g0 + (size_t)j * NN + UU);
    }
#pragma unroll
    for (int h = 0; h < 2; ++h) {
        ushort4 nz[8], nf[8];
        if (h == 0) {
#pragma unroll
            for (int j = 0; j < 8; ++j) {
                nz[j] = *(const ushort4*)(gates + g0 + (size_t)(8 + j) * NN);
                nf[j] = *(const ushort4*)(gates + g0 + (size_t)(8 + j) * NN + UU);
            }
        }
#pragma unroll
        for (int j = 0; j < 8; ++j) {
            float f0 = sigf(bf2f(bf_[j].x)), z0 = tanh_(bf2f(bz[j].x));
            float f1 = sigf(bf2f(bf_[j].y)), z1 = tanh_(bf2f(bz[j].y));
            float f2 = sigf(bf2f(bf_[j].z)), z2 = tanh_(bf2f(bz[j].z));
            float f3 = sigf(bf2f(bf_[j].w)), z3 = tanh_(bf2f(bz[j].w));
            c0 = f0 * c0 + (1.0f - f0) * z0; F0 *= f0;
            c1 = f1 * c1 + (1.0f - f1) * z1; F1 *= f1;
            c2 = f2 * c2 + (1.0f - f2) * z2; F2 *= f2;
            c3 = f3 * c3 + (1.0f - f3) * z3; F3 *= f3;
        }
        if (h == 0) {
#pragma unroll
            for (int j = 0; j < 8; ++j) { bz[j] = nz[j]; bf_[j] = nf[j]; }
        }
    }
    size_t ci = ((size_t)b * NCH + chunk) * UU + u;
    *(float4*)(Fp + ci) = make_float4(F0, F1, F2, F3);
    *(float4*)(Ce + ci) = make_float4(c0, c1, c2, c3);
}

// ---- 4) pass B: sequential scan over chunks -> carry-in per chunk ----
__global__ __launch_bounds__(128) void k_scanB(const float* __restrict__ Fp,
                        const float* __restrict__ Ce, float* __restrict__ Cin) {
    int gid = blockIdx.x * 128 + threadIdx.x;   // 0..4095
    int bb = gid >> 9;           // batch
    int uu = gid & 511;          // unit
    size_t base = (size_t)bb * NCH * UU + uu;
    float c = 0.0f;
    for (int k0 = 0; k0 < NCH; k0 += 8) {
        float F[8], E[8];
#pragma unroll
        for (int j = 0; j < 8; ++j) {
            F[j] = Fp[base + (size_t)(k0 + j) * UU];
            E[j] = Ce[base + (size_t)(k0 + j) * UU];
        }
#pragma unroll
        for (int j = 0; j < 8; ++j) {
            Cin[base + (size_t)(k0 + j) * UU] = c;
            c = F[j] * c + E[j];
        }
    }
}

// ---- 5) pass C: replay chunk with true carry, emit out = o * c ----
__global__ __launch_bounds__(128) void k_scanC(const unsigned short* __restrict__ gates,
                        const float* __restrict__ Cin, float* __restrict__ out) {
    const int chunk = blockIdx.x;
    const int b     = blockIdx.y;
    const int u     = threadIdx.x << 2;
    const size_t g0 = ((size_t)b * TT + (size_t)chunk * CHL) * NN + u;
    size_t o = ((size_t)b * TT + (size_t)chunk * CHL) * UU + u;

    size_t ci = ((size_t)b * NCH + chunk) * UU + u;
    float4 cv = *(const float4*)(Cin + ci);
    float c0 = cv.x, c1 = cv.y, c2 = cv.z, c3 = cv.w;

    ushort4 bz[4], bf_[4], bo[4];
#pragma unroll
    for (int j = 0; j < 4; ++j) {
        bz[j]  = *(const ushort4*)(gates + g0 + (size_t)j * NN);
        bf_[j] = *(const ushort4*)(gates + g0 + (size_t)j * NN + UU);
        bo[j]  = *(const ushort4*)(gates + g0 + (size_t)j * NN + 2 * UU);
    }
#pragma unroll
    for (int k = 0; k < 4; ++k) {
        ushort4 nz[4], nf[4], no[4];
        if (k < 3) {
#pragma unroll
            for (int j = 0; j < 4; ++j) {
                size_t gg = g0 + (size_t)((k + 1) * 4 + j) * NN;
                nz[j] = *(const ushort4*)(gates + gg);
                nf[j] = *(const ushort4*)(gates + gg + UU);
                no[j] = *(const ushort4*)(gates + gg + 2 * UU);
            }
        }
#pragma unroll
        for (int j = 0; j < 4; ++j) {
            float f0 = sigf(bf2f(bf_[j].x)), z0 = tanh_(bf2f(bz[j].x)), o0 = sigf(bf2f(bo[j].x));
            float f1 = sigf(bf2f(bf_[j].y)), z1 = tanh_(bf2f(bz[j].y)), o1 = sigf(bf2f(bo[j].y));
            float f2 = sigf(bf2f(bf_[j].z)), z2 = tanh_(bf2f(bz[j].z)), o2 = sigf(bf2f(bo[j].z));
            float f3 = sigf(bf2f(bf_[j].w)), z3 = tanh_(bf2f(bz[j].w)), o3 = sigf(bf2f(bo[j].w));
            c0 = f0 * c0 + (1.0f - f0) * z0;
            c1 = f1 * c1 + (1.0f - f1) * z1;
            c2 = f2 * c2 + (1.0f - f2) * z2;
            c3 = f3 * c3 + (1.0f - f3) * z3;
            f32x4 ov = { o0 * c0, o1 * c1, o2 * c2, o3 * c3 };
            __builtin_nontemporal_store(ov, (f32x4*)(out + o));
            o += UU;
        }
        if (k < 3) {
#pragma unroll
            for (int j = 0; j < 4; ++j) { bz[j] = nz[j]; bf_[j] = nf[j]; bo[j] = no[j]; }
        }
    }
}

extern "C" void kernel_launch(void* const* d_in, const int* in_sizes, int n_in,
                              void* d_out, int out_size, void* d_ws, size_t ws_size,
                              hipStream_t stream) {
    const float* x    = (const float*)d_in[0];
    const float* kern = (const float*)d_in[1];
    const float* bias = (const float*)d_in[2];
    float* out = (float*)d_out;
    char* ws = (char*)d_ws;

    // workspace layout (bytes)
    unsigned short* xpad  = (unsigned short*)(ws + 0);           // 8*4097*512*2   = 33,562,624
    unsigned short* kT    = (unsigned short*)(ws + 33562624);    // 1536*1024*2    =  3,145,728
    unsigned short* gates = (unsigned short*)(ws + 36708352);    // 32768*1536*2   = 100,663,296
    float* Fp  = (float*)(ws + 137371648);                       // 8*256*512*4    =  4,194,304
    float* Ce  = (float*)(ws + 141565952);                       //                =  4,194,304
    float* Cin = (float*)(ws + 145760256);                       //                =  4,194,304
    // total: 149,954,560 bytes

    hipLaunchKernelGGL(k_prep,  dim3(2049 + 24, 8), dim3(256), 0, stream, x, xpad, kern, kT);
    hipLaunchKernelGGL(k_gemm,  dim3(3072),         dim3(256), 0, stream, xpad, kT, bias, gates);
    hipLaunchKernelGGL(k_scanA, dim3(NCH, BB),      dim3(128), 0, stream, gates, Fp, Ce);
    hipLaunchKernelGGL(k_scanB, dim3(32),           dim3(128), 0, stream, Fp, Ce, Cin);
    hipLaunchKernelGGL(k_scanC, dim3(NCH, BB),      dim3(128), 0, stream, gates, Cin, out);
}